// Round 13
// baseline (1689.519 us; speedup 1.0000x reference)
//
#include <hip/hip_runtime.h>
#include <cstdint>
#include <cstddef>

// Problem constants
#define BB   64     // batch
#define TT   512    // time steps
#define HH   256    // hidden
#define G4   1024   // 4*H
#define NL   8      // layers
#define NW   32     // workgroups per layer (hidden-unit slices)
#define HPW  8      // hidden units per WG
#define NR   32     // gate rows per WG (4 gates * HPW)

// Watchdog: poll/retry breaks after this many iterations and proceeds
// (bounded wrong-answer instead of GPU hang). Never triggers when sound.
#define POLL_BOUND (1 << 15)

// fp16 NaN sentinel (memset byte 0x7F -> every half = 0x7F7F). Legit h values
// are o*tanh(c) in (-1,1) -- never NaN -- so a sentinel dword uniquely means
// "slot not yet written". Checking ALL 4 dwords of a 16B fragment tolerates
// store tearing down to 4B granularity (partial commit leaves >=1 sentinel).
#define SENT 0x7F7F7F7F

typedef _Float16 half8 __attribute__((ext_vector_type(8)));
typedef float   floatx4 __attribute__((ext_vector_type(4)));
typedef int     intx4  __attribute__((ext_vector_type(4)));

__device__ __forceinline__ float sigm(float v)   { return 1.0f / (1.0f + __expf(-v)); }
__device__ __forceinline__ float tanh_f(float v) { return 1.0f - 2.0f / (__expf(2.0f * v) + 1.0f); }

// ---- coherence helpers ----------------------------------------------------
// Forward edge (cross-layer): PROVEN strict protocol -- data sc0sc1, vmcnt(0)
// ack, flag sc0sc1, consumer polls flag then plain-cached first-touch reads.
// Recurrent edge (intra-layer, the critical path): DATA-AS-FLAG -- hseq is
// NaN-prefilled; producers just store (no ack/flag); consumers sc0sc1-load
// and retry while any dword == SENT. No ordering assumptions at all: loads
// bypass caches, each 16B is one access, sentinel check detects staleness.
// Session ledger: 2B sc0sc1 publishes -> 2x write amplification (R7);
// per-wave acks serialized before polls -> +1.2-2.4us/step (R7/R9);
// wave0-publish || others-poll overlap essential (R9->R10); input-half hoist
// + all-lane cell = -240us (R11); fc-MFMA + setprio = -265us (R12).
__device__ __forceinline__ void gstore8_x(_Float16* p, half8 d) {
  asm volatile("global_store_dwordx4 %0, %1, off sc0 sc1" :: "v"(p), "v"(d) : "memory");
}
__device__ __forceinline__ void stdword_x(int* p, int v) {
  asm volatile("global_store_dword %0, %1, off sc0 sc1" :: "v"(p), "v"(v) : "memory");
}
__device__ __forceinline__ void wait_vm0() {
  asm volatile("s_waitcnt vmcnt(0)" ::: "memory");
}
__device__ __forceinline__ int ldflag_x(const int* p) {
  int v; asm volatile("global_load_dword %0, %1, off sc0 sc1" : "=v"(v) : "v"(p) : "memory");
  wait_vm0(); return v;
}
// raw 16B sc0sc1 load, NO wait -- batch with wait_vm0() + sched_barrier(0)
__device__ __forceinline__ intx4 ld16_x(const _Float16* p) {
  intx4 v;
  asm volatile("global_load_dwordx4 %0, %1, off sc0 sc1" : "=v"(v) : "v"(p) : "memory");
  return v;
}

// hseq layout per layer: [t][kblk=H/8=32][b=64][8] fp16 (MFMA A-fragment friendly)
#define TSTRIDE ((size_t)32 * BB * 8)         // 16384 elems per t
#define LSTRIDE ((size_t)TT * TSTRIDE)        // 8,388,608 elems per layer (16 MB)

// ---------------------------------------------------------------------------
// xg0 table: table[v][n] = sum_e emb[v][e] * Wih0[n][e]   (biases NOT included)
__global__ void build_xg0(const float* __restrict__ emb, const float* __restrict__ Wih0,
                          float* __restrict__ table) {
  int i = blockIdx.x * 256 + threadIdx.x;
  if (i >= 23 * G4) return;
  int v = i >> 10, n = i & (G4 - 1);
  float a = 0.f;
#pragma unroll
  for (int e = 0; e < 16; ++e) a += emb[v * 16 + e] * Wih0[n * 16 + e];
  table[i] = a;
}

// ---------------------------------------------------------------------------
// Persistent pipelined LSTM -- R12 structure with the recurrent sync legs
// replaced by data-as-flag (see helpers comment):
//   per step: [hoist input MFMA] [p2 fwd poll only] [barrier A]
//   [rec: 8x sc0sc1 loads -> vmcnt(0) (also acks wave0's h(t-1) publish!)
//    -> deferred fwd-flag release (cnt=t) -> sentinel validate+retry]
//   [16 rec MFMAs] [shfl gate exchange] [all-lane cell] [barrier C]
//   [wave0: issue h(t) stores, NO wait, NO flag]
// The producer-side ack+release and consumer-side observe legs vanish from
// the critical path; the deferred release rides the rec-load vmcnt for free.
__global__ __launch_bounds__(256, 1) void lstm_pipeline(
    const int*   __restrict__ x,         // [B][T]
    const float* __restrict__ Wih_rest,  // [7][1024][256]
    const float* __restrict__ Whh,       // [8][1024][256]
    const float* __restrict__ bih,       // [8][1024]
    const float* __restrict__ bhh,       // [8][1024]
    const float* __restrict__ xg0t,      // [23][1024]
    _Float16* __restrict__ hseq,         // NL * LSTRIDE fp16 (NaN-prefilled)
    int* __restrict__ cnt)               // [NL][NW] fwd step counters (IF$)
{
  const int l   = blockIdx.x & 7;
  const int w   = blockIdx.x >> 3;
  const int tid = threadIdx.x;
  const int lane = tid & 63;
  const int p    = tid >> 6;        // wave index = M-tile index (batch/16)

  __shared__ __align__(16) _Float16 wlds[64 * NR * 8]; // [kc 0..63][n 0..31][8]
  __shared__ __align__(16) _Float16 hl[BB * 8];        // h staging for publish
  __shared__ float  blds[NR];
  __shared__ float  tlds[23 * NR];

  // ---- one-time init: gather this WG's 32 gate rows into LDS as fp16 ----
  // wlds n-rows: 0..7 = gate i (units 0..7), 8..15 = f, 16..23 = g, 24..31 = o
  for (int idx = tid; idx < 64 * NR; idx += 256) {
    int kc = idx >> 5;          // 0..31 input half, 32..63 recurrent half
    int n  = idx & 31;
    int g = n >> 3, jl = n & 7;
    int gr = g * 256 + w * HPW + jl;
    float v[8];
    if (kc < 32) {
      if (l == 0) { for (int j = 0; j < 8; ++j) v[j] = 0.f; }
      else {
        const float* src = Wih_rest + ((size_t)(l - 1) * G4 + gr) * HH + kc * 8;
        for (int j = 0; j < 8; ++j) v[j] = src[j];
      }
    } else {
      const float* src = Whh + ((size_t)l * G4 + gr) * HH + (kc - 32) * 8;
      for (int j = 0; j < 8; ++j) v[j] = src[j];
    }
    _Float16* dst = wlds + (size_t)idx * 8;
    for (int j = 0; j < 8; ++j) dst[j] = (_Float16)v[j];
  }
  if (tid < NR) {
    int g = tid >> 3, jl = tid & 7;
    int gr = g * 256 + w * HPW + jl;
    blds[tid] = bih[l * G4 + gr] + bhh[l * G4 + gr];
  }
  if (l == 0) {
    for (int idx = tid; idx < 23 * NR; idx += 256) {
      int v = idx >> 5, n = idx & 31;
      int g = n >> 3, jl = n & 7;
      tlds[idx] = xg0t[v * G4 + g * 256 + w * HPW + jl];
    }
  }
  // agent-scope acquire: invalidate stale L1/L2 lines before cached fwd reads
  if (tid == 0) (void)__hip_atomic_load(cnt, __ATOMIC_ACQUIRE, __HIP_MEMORY_SCOPE_AGENT);
  __syncthreads();

  const int arow = p * 16 + (lane & 15);  // A-fragment batch row
  const int kq   = lane >> 4;             // quarter-wave -> k chunk within tile
  const int n0   = lane & 15;             // B-fragment col (tile 0)
  const int n1   = 16 + n0;               // B-fragment col (tile 1)
  const int cu   = lane & 7;              // cell: unit within slice
  const bool lowh = (n0 < 8);             // lo half: rows 0,1; hi half: rows 2,3
  const int roff = lowh ? 0 : 2;
  const int rowb = p * 16 + kq * 4;       // first of this quarter's 4 batch rows

  const _Float16* hin  = hseq + (size_t)(l > 0 ? l - 1 : 0) * LSTRIDE;
  _Float16*       hrec = hseq + (size_t)l * LSTRIDE;

  const float bi = blds[cu], bf = blds[8 + cu], bg = blds[16 + cu], bo = blds[24 + cu];

  float cst[2] = {0.f, 0.f};   // c-state: batch rowb+roff+rr, unit w*8+cu

  for (int t = 0; t < TT; ++t) {
    floatx4 acc0 = {0.f, 0.f, 0.f, 0.f};   // tile0: cols = {i x8, f x8}
    floatx4 acc1 = {0.f, 0.f, 0.f, 0.f};   // tile1: cols = {g x8, o x8}

    // ---- (H) hoisted input half (t>0): h^{l-1}(t) was confirmed by the
    //      previous step's lookahead poll -> compute during any fwd wait ----
    if (l > 0 && t > 0) {
      const _Float16* ain = hin + (size_t)t * TSTRIDE;
      half8 aA[8];
#pragma unroll
      for (int kt = 0; kt < 8; ++kt) {
        int kc = kt * 4 + kq;
        aA[kt] = *(const half8*)(ain + ((size_t)(kc * 64 + arow) << 3));
      }
#pragma unroll
      for (int kt = 0; kt < 8; ++kt) {
        int kc = kt * 4 + kq;
        half8 w0 = *(const half8*)(wlds + ((kc * 32 + n0) << 3));
        half8 w1 = *(const half8*)(wlds + ((kc * 32 + n1) << 3));
        acc0 = __builtin_amdgcn_mfma_f32_16x16x32_f16(aA[kt], w0, acc0, 0, 0, 0);
        acc1 = __builtin_amdgcn_mfma_f32_16x16x32_f16(aA[kt], w1, acc1, 0, 0, 0);
      }
    }

    // ---- fwd poll only (wave2), one-step lookahead for the next hoist.
    //      Own-layer sync is now data-as-flag -- p3 poll DELETED. ----
    if (l > 0 && p == 2) {
      const int tgt = (t + 2 < TT) ? t + 2 : TT;
      const int* f = cnt + (l - 1) * NW;
      for (int it = 0; it < POLL_BOUND; ++it) {
        int v = ldflag_x(f + (lane & 31));
        if (__all(v >= tgt)) break;
        __builtin_amdgcn_s_sleep(1);
      }
    }
    __syncthreads();   // barrier A (hl-reuse ordering + fwd-confirm fence)

    // ---- t==0 input half (fwd>=2 just confirmed, covers >=1) ----
    if (l > 0 && t == 0) {
      const _Float16* ain = hin;   // t = 0
      half8 aA[8];
#pragma unroll
      for (int kt = 0; kt < 8; ++kt) {
        int kc = kt * 4 + kq;
        aA[kt] = *(const half8*)(ain + ((size_t)(kc * 64 + arow) << 3));
      }
#pragma unroll
      for (int kt = 0; kt < 8; ++kt) {
        int kc = kt * 4 + kq;
        half8 w0 = *(const half8*)(wlds + ((kc * 32 + n0) << 3));
        half8 w1 = *(const half8*)(wlds + ((kc * 32 + n1) << 3));
        acc0 = __builtin_amdgcn_mfma_f32_16x16x32_f16(aA[kt], w0, acc0, 0, 0, 0);
        acc1 = __builtin_amdgcn_mfma_f32_16x16x32_f16(aA[kt], w1, acc1, 0, 0, 0);
      }
    }

    // ---- recurrent half: DATA-AS-FLAG acquire + 16 MFMAs ----
    if (t > 0) {
      const _Float16* ain = hrec + (size_t)(t - 1) * TSTRIDE;
      const _Float16* ap[8];
      intx4 raw[8];
#pragma unroll
      for (int kt = 0; kt < 8; ++kt) {
        int kc = kt * 4 + kq;
        ap[kt]  = ain + ((size_t)(kc * 64 + arow) << 3);
        raw[kt] = ld16_x(ap[kt]);
      }
      wait_vm0();                          // rec loads + wave0's h(t-1) store ack
      __builtin_amdgcn_sched_barrier(0);   // rule #18: pin reads after the wait
      // deferred fwd release: h(t-1) stores are acked by the wait above
      if (tid == 0) stdword_x(cnt + l * NW + w, t);
      // sentinel validation + bounded retry (memory latency is the backoff)
      for (int it = 0; it < POLL_BOUND; ++it) {
        int bad = 0;
#pragma unroll
        for (int kt = 0; kt < 8; ++kt) {
          const intx4 r = raw[kt];
          const int b = (r.x == SENT) | (r.y == SENT) | (r.z == SENT) | (r.w == SENT);
          bad |= b << kt;
        }
        if (!__any(bad != 0)) break;
#pragma unroll
        for (int kt = 0; kt < 8; ++kt)
          if (bad & (1 << kt)) raw[kt] = ld16_x(ap[kt]);
        wait_vm0();
        __builtin_amdgcn_sched_barrier(0);
      }
#pragma unroll
      for (int kt = 0; kt < 8; ++kt) {
        int kc = kt * 4 + kq;
        union { intx4 i; half8 h; } u; u.i = raw[kt];
        half8 w0 = *(const half8*)(wlds + (((32 + kc) * 32 + n0) << 3));
        half8 w1 = *(const half8*)(wlds + (((32 + kc) * 32 + n1) << 3));
        acc0 = __builtin_amdgcn_mfma_f32_16x16x32_f16(u.h, w0, acc0, 0, 0, 0);
        acc1 = __builtin_amdgcn_mfma_f32_16x16x32_f16(u.h, w1, acc1, 0, 0, 0);
      }
    }

    // ---- (J2) packed gate exchange: lanes c<->c+8 swap the two C-rows the
    //      partner needs. After this BOTH halves hold complete i/f/g/o. ----
    const float sa0 = lowh ? acc0[2] : acc0[0];
    const float sa1 = lowh ? acc0[3] : acc0[1];
    const float sb0 = lowh ? acc1[2] : acc1[0];
    const float sb1 = lowh ? acc1[3] : acc1[1];
    const float ra0 = __shfl_xor(sa0, 8);
    const float ra1 = __shfl_xor(sa1, 8);
    const float rb0 = __shfl_xor(sb0, 8);
    const float rb1 = __shfl_xor(sb1, 8);

    // ---- cell on ALL lanes: 2 cells/lane (rows rowb+roff, rowb+roff+1) ----
#pragma unroll
    for (int rr = 0; rr < 2; ++rr) {
      const int r = roff + rr;
      const float own0 = acc0[r], own1 = acc1[r];
      const float oth0 = rr ? ra1 : ra0;
      const float oth1 = rr ? rb1 : rb0;
      float gi = (lowh ? own0 : oth0) + bi;
      float gf = (lowh ? oth0 : own0) + bf;
      float gg = (lowh ? own1 : oth1) + bg;
      float go = (lowh ? oth1 : own1) + bo;
      if (l == 0) {
        const int xv = x[(rowb + r) * TT + t];
        const float* tb = tlds + xv * NR;
        gi += tb[cu]; gf += tb[8 + cu]; gg += tb[16 + cu]; go += tb[24 + cu];
      }
      const float iv = sigm(gi), fv = sigm(gf), gv = tanh_f(gg), ov = sigm(go);
      cst[rr] = fv * cst[rr] + iv * gv;
      const float hv = ov * tanh_f(cst[rr]);
      hl[(rowb + r) * 8 + cu] = (_Float16)hv;
    }
    __syncthreads();   // barrier C: hl complete

    // ---- publish: wave0 ISSUES the 1KB slice stores and moves on.
    //      No ack, no flag here -- consumers self-validate; the ack rides
    //      next step's rec-load vmcnt; the fwd flag is released there. ----
    if (tid < 64) {
      __builtin_amdgcn_s_setprio(1);
      half8 hv = *(const half8*)(hl + tid * 8);
      gstore8_x(hrec + (size_t)t * TSTRIDE + ((size_t)(w * 64 + tid) << 3), hv);
      __builtin_amdgcn_s_setprio(0);
    }
    // next iteration's barrier A closes the step
  }

  // ---- epilogue: ack h(TT-1) stores + final fwd flag ----
  if (tid < 64) {
    wait_vm0();
    if (tid == 0) stdword_x(cnt + l * NW + w, TT);
  }
}

// ---------------------------------------------------------------------------
// Final projection via MFMA: out[b][t][v] = h7[b][t][:] . fc_w[v][:] + fc_b[v]
// h7 is stored in the exact A-fragment layout [kc][b][8]. N = 23 padded to 32
// (2 tiles). Split-precision weights: w = w_hi + w_lo * 2^-11, both fp16
// (w_lo pre-scaled by 2^11 to stay in normal range); two accumulator sets
// keep the quantization error ~2^-22 relative -- no threshold risk.
__global__ __launch_bounds__(256) void fc_kernel(
    const _Float16* __restrict__ hseq7,  // [T][32][64][8] fp16
    const float* __restrict__ fcw,       // [23][256]
    const float* __restrict__ fcb,       // [23]
    float* __restrict__ out)             // [64][512][23]
{
  const int t = blockIdx.x;
  const int tid = threadIdx.x;
  const int lane = tid & 63;
  const int p = tid >> 6;

  __shared__ __align__(16) _Float16 whi[32 * 32 * 8];  // [kc][n][8] 16KB
  __shared__ __align__(16) _Float16 wlo[32 * 32 * 8];  // residual * 2^11
  __shared__ float bbuf[32];

  for (int idx = tid; idx < 32 * 32; idx += 256) {
    int kc = idx >> 5, n = idx & 31;
    _Float16* dh = whi + (size_t)idx * 8;
    _Float16* dl = wlo + (size_t)idx * 8;
    if (n < 23) {
      const float* src = fcw + n * 256 + kc * 8;
      for (int j = 0; j < 8; ++j) {
        float v = src[j];
        _Float16 hi = (_Float16)v;
        dh[j] = hi;
        dl[j] = (_Float16)((v - (float)hi) * 2048.0f);
      }
    } else {
      for (int j = 0; j < 8; ++j) { dh[j] = (_Float16)0.f; dl[j] = (_Float16)0.f; }
    }
  }
  if (tid < 32) bbuf[tid] = (tid < 23) ? fcb[tid] : 0.f;
  __syncthreads();

  const int arow = p * 16 + (lane & 15);
  const int kq   = lane >> 4;
  const int n0   = lane & 15;
  const int n1   = 16 + n0;

  const _Float16* src = hseq7 + (size_t)t * TSTRIDE;
  floatx4 a0h = {0.f,0.f,0.f,0.f}, a1h = {0.f,0.f,0.f,0.f};
  floatx4 a0l = {0.f,0.f,0.f,0.f}, a1l = {0.f,0.f,0.f,0.f};
#pragma unroll
  for (int kt = 0; kt < 8; ++kt) {
    int kc = kt * 4 + kq;
    half8 a  = *(const half8*)(src + ((size_t)(kc * 64 + arow) << 3));
    half8 h0 = *(const half8*)(whi + ((kc * 32 + n0) << 3));
    half8 h1 = *(const half8*)(whi + ((kc * 32 + n1) << 3));
    half8 l0 = *(const half8*)(wlo + ((kc * 32 + n0) << 3));
    half8 l1 = *(const half8*)(wlo + ((kc * 32 + n1) << 3));
    a0h = __builtin_amdgcn_mfma_f32_16x16x32_f16(a, h0, a0h, 0, 0, 0);
    a1h = __builtin_amdgcn_mfma_f32_16x16x32_f16(a, h1, a1h, 0, 0, 0);
    a0l = __builtin_amdgcn_mfma_f32_16x16x32_f16(a, l0, a0l, 0, 0, 0);
    a1l = __builtin_amdgcn_mfma_f32_16x16x32_f16(a, l1, a1l, 0, 0, 0);
  }

  // C layout: col = lane&15 (vocab), row = kq*4 + r (+p*16) (batch)
  const float rs = 1.0f / 2048.0f;
#pragma unroll
  for (int r = 0; r < 4; ++r) {
    int b = p * 16 + kq * 4 + r;
    out[((size_t)b * TT + t) * 23 + n0] = a0h[r] + a0l[r] * rs + bbuf[n0];
    if (n1 < 23)
      out[((size_t)b * TT + t) * 23 + n1] = a1h[r] + a1l[r] * rs + bbuf[n1];
  }
}

// ---------------------------------------------------------------------------
extern "C" void kernel_launch(void* const* d_in, const int* in_sizes, int n_in,
                              void* d_out, int out_size, void* d_ws, size_t ws_size,
                              hipStream_t stream) {
  const int*   x        = (const int*)d_in[0];
  const float* emb      = (const float*)d_in[1];
  const float* Wih0     = (const float*)d_in[2];
  const float* Wih_rest = (const float*)d_in[3];
  const float* Whh      = (const float*)d_in[4];
  const float* bihp     = (const float*)d_in[5];
  const float* bhhp     = (const float*)d_in[6];
  const float* fcw      = (const float*)d_in[7];
  const float* fcb      = (const float*)d_in[8];
  float* out = (float*)d_out;

  char* ws = (char*)d_ws;
  // ws layout (proven): cnt @0 (1KB used) | table @16384 | hseq @131072 (128MB)
  int*      cnt   = (int*)ws;
  float*    table = (float*)(ws + 16384);              // 23*1024*4 = 94208 B
  _Float16* hseq  = (_Float16*)(ws + 131072);          // 8 * 16 MB

  hipMemsetAsync(ws, 0, 16384, stream);                // counters
  // NaN-prefill hseq: every fp16 becomes 0x7F7F (the data-as-flag sentinel)
  hipMemsetAsync(ws + 131072, 0x7F, (size_t)NL * LSTRIDE * sizeof(_Float16), stream);
  build_xg0<<<(23 * G4 + 255) / 256, 256, 0, stream>>>(emb, Wih0, table);
  lstm_pipeline<<<NL * NW, 256, 0, stream>>>(x, Wih_rest, Whh, bihp, bhhp, table, hseq, cnt);
  fc_kernel<<<TT, 256, 0, stream>>>(hseq + (size_t)7 * LSTRIDE, fcw, fcb, out);
}

// Round 14
// 1685.471 us; speedup vs baseline: 1.0024x; 1.0024x over previous
//
#include <hip/hip_runtime.h>
#include <cstdint>
#include <cstddef>

// Problem constants
#define BB   64     // batch
#define TT   512    // time steps
#define HH   256    // hidden
#define G4   1024   // 4*H
#define NL   8      // layers
#define NW   32     // workgroups per layer (hidden-unit slices)
#define HPW  8      // hidden units per WG
#define NR   32     // gate rows per WG (4 gates * HPW)

// Watchdog: poll breaks after this many iterations and proceeds (bounded
// wrong-answer instead of GPU hang). Never triggers when protocol is sound.
#define POLL_BOUND (1 << 15)

typedef _Float16 half8 __attribute__((ext_vector_type(8)));
typedef float   floatx4 __attribute__((ext_vector_type(4)));
typedef unsigned int u32;

__device__ __forceinline__ float sigm(float v)   { return 1.0f / (1.0f + __expf(-v)); }
__device__ __forceinline__ float tanh_f(float v) { return 1.0f - 2.0f / (__expf(2.0f * v) + 1.0f); }

// ---- coherence helpers (ONLY the proven system-scope primitives) ----------
// Producer: data stores sc0sc1 -> s_waitcnt vmcnt(0) -> flag store sc0sc1.
// Consumer: poll flag sc0sc1; then PLAIN cached loads of the data (each data
// address is written exactly once per launch and only read after the flag:
// first-touch L2 fill pulls post-store bytes from IF$).
// Session ledger: 2B sc0sc1 publishes -> 2x write amplification (R7);
// per-wave acks serialized before polls -> +1.2-2.4us/step (R7/R9);
// wave0-publish || others-poll overlap essential (R9->R10); input-half hoist
// + all-lane cell = -240us (R11); fc-MFMA + setprio = -265us (R12);
// UNCACHED consumer reads destroy the 32-way L2 fill sharing -> +90us (R13,
// data-as-flag refuted) -- consumer h reads MUST stay cached.
__device__ __forceinline__ void gstore8_x(_Float16* p, half8 d) {
  asm volatile("global_store_dwordx4 %0, %1, off sc0 sc1" :: "v"(p), "v"(d) : "memory");
}
__device__ __forceinline__ void stdword_x(int* p, int v) {
  asm volatile("global_store_dword %0, %1, off sc0 sc1" :: "v"(p), "v"(v) : "memory");
}
__device__ __forceinline__ void wait_vm0() {
  asm volatile("s_waitcnt vmcnt(0)" ::: "memory");
}
__device__ __forceinline__ int ldflag_x(const int* p) {
  int v; asm volatile("global_load_dword %0, %1, off sc0 sc1" : "=v"(v) : "v"(p) : "memory");
  wait_vm0(); return v;
}

// hseq layout per layer: [t][kblk=H/8=32][b=64][8] fp16 (MFMA A-fragment friendly)
#define TSTRIDE ((size_t)32 * BB * 8)         // 16384 elems per t
#define LSTRIDE ((size_t)TT * TSTRIDE)        // 8,388,608 elems per layer (16 MB)

// ---------------------------------------------------------------------------
// xg0 table: table[v][n] = sum_e emb[v][e] * Wih0[n][e]   (biases NOT included)
__global__ void build_xg0(const float* __restrict__ emb, const float* __restrict__ Wih0,
                          float* __restrict__ table) {
  int i = blockIdx.x * 256 + threadIdx.x;
  if (i >= 23 * G4) return;
  int v = i >> 10, n = i & (G4 - 1);
  float a = 0.f;
#pragma unroll
  for (int e = 0; e < 16; ++e) a += emb[v * 16 + e] * Wih0[n * 16 + e];
  table[i] = a;
}

// ---------------------------------------------------------------------------
// Persistent pipelined LSTM -- R12 structure (proven 1601us total) + ONE
// change: publisher L2 SELF-WARM. After wave0's ack+release, its slice data
// is final; a cached read pulls it into the XCD-shared L2 BEFORE the 32
// consumers' post-flag loads (which currently all merge-wait on the same IF$
// fetches, ~900cy on the critical path). The warm uses global_load_lds into
// a never-read LDS scratch: no VGPR writeback hazard, vmcnt-tracked, and the
// entries are older than any compiler-counted load so vmcnt(N) waits remain
// conservative-correct. Write-once discipline holds: the warm is the FIRST
// read of those addresses (consumers read only after observing the flag), so
// no stale L1/L2 line can exist.
__global__ __launch_bounds__(256, 1) void lstm_pipeline(
    const int*   __restrict__ x,         // [B][T]
    const float* __restrict__ Wih_rest,  // [7][1024][256]
    const float* __restrict__ Whh,       // [8][1024][256]
    const float* __restrict__ bih,       // [8][1024]
    const float* __restrict__ bhh,       // [8][1024]
    const float* __restrict__ xg0t,      // [23][1024]
    _Float16* __restrict__ hseq,         // NL * LSTRIDE fp16
    int* __restrict__ cnt)               // [NL][NW] step counters (IF$)
{
  const int l   = blockIdx.x & 7;
  const int w   = blockIdx.x >> 3;
  const int tid = threadIdx.x;
  const int lane = tid & 63;
  const int p    = tid >> 6;        // wave index = M-tile index (batch/16)

  __shared__ __align__(16) _Float16 wlds[64 * NR * 8]; // [kc 0..63][n 0..31][8]
  __shared__ __align__(16) _Float16 hl[BB * 8];        // h staging for publish
  __shared__ __align__(16) _Float16 warmsc[64 * 8];    // warm sink (never read)
  __shared__ float  blds[NR];
  __shared__ float  tlds[23 * NR];

  // ---- one-time init: gather this WG's 32 gate rows into LDS as fp16 ----
  // wlds n-rows: 0..7 = gate i (units 0..7), 8..15 = f, 16..23 = g, 24..31 = o
  for (int idx = tid; idx < 64 * NR; idx += 256) {
    int kc = idx >> 5;          // 0..31 input half, 32..63 recurrent half
    int n  = idx & 31;
    int g = n >> 3, jl = n & 7;
    int gr = g * 256 + w * HPW + jl;
    float v[8];
    if (kc < 32) {
      if (l == 0) { for (int j = 0; j < 8; ++j) v[j] = 0.f; }
      else {
        const float* src = Wih_rest + ((size_t)(l - 1) * G4 + gr) * HH + kc * 8;
        for (int j = 0; j < 8; ++j) v[j] = src[j];
      }
    } else {
      const float* src = Whh + ((size_t)l * G4 + gr) * HH + (kc - 32) * 8;
      for (int j = 0; j < 8; ++j) v[j] = src[j];
    }
    _Float16* dst = wlds + (size_t)idx * 8;
    for (int j = 0; j < 8; ++j) dst[j] = (_Float16)v[j];
  }
  if (tid < NR) {
    int g = tid >> 3, jl = tid & 7;
    int gr = g * 256 + w * HPW + jl;
    blds[tid] = bih[l * G4 + gr] + bhh[l * G4 + gr];
  }
  if (l == 0) {
    for (int idx = tid; idx < 23 * NR; idx += 256) {
      int v = idx >> 5, n = idx & 31;
      int g = n >> 3, jl = n & 7;
      tlds[idx] = xg0t[v * G4 + g * 256 + w * HPW + jl];
    }
  }
  // agent-scope acquire: invalidate stale L1/L2 lines before cached h reads
  if (tid == 0) (void)__hip_atomic_load(cnt, __ATOMIC_ACQUIRE, __HIP_MEMORY_SCOPE_AGENT);
  __syncthreads();

  const int arow = p * 16 + (lane & 15);  // A-fragment batch row
  const int kq   = lane >> 4;             // quarter-wave -> k chunk within tile
  const int n0   = lane & 15;             // B-fragment col (tile 0)
  const int n1   = 16 + n0;               // B-fragment col (tile 1)
  const int cu   = lane & 7;              // cell: unit within slice
  const bool lowh = (n0 < 8);             // lo half: rows 0,1; hi half: rows 2,3
  const int roff = lowh ? 0 : 2;
  const int rowb = p * 16 + kq * 4;       // first of this quarter's 4 batch rows

  const _Float16* hin  = hseq + (size_t)(l > 0 ? l - 1 : 0) * LSTRIDE;
  _Float16*       hrec = hseq + (size_t)l * LSTRIDE;

  const float bi = blds[cu], bf = blds[8 + cu], bg = blds[16 + cu], bo = blds[24 + cu];

  float cst[2] = {0.f, 0.f};   // c-state: batch rowb+roff+rr, unit w*8+cu

  for (int t = 0; t < TT; ++t) {
    floatx4 acc0 = {0.f, 0.f, 0.f, 0.f};   // tile0: cols = {i x8, f x8}
    floatx4 acc1 = {0.f, 0.f, 0.f, 0.f};   // tile1: cols = {g x8, o x8}

    // ---- (H) hoisted input half (t>0): h^{l-1}(t) was confirmed by the
    //      previous step's lookahead poll -> compute during the flag wait ----
    if (l > 0 && t > 0) {
      const _Float16* ain = hin + (size_t)t * TSTRIDE;
      half8 aA[8];
#pragma unroll
      for (int kt = 0; kt < 8; ++kt) {
        int kc = kt * 4 + kq;
        aA[kt] = *(const half8*)(ain + ((size_t)(kc * 64 + arow) << 3));
      }
#pragma unroll
      for (int kt = 0; kt < 8; ++kt) {
        int kc = kt * 4 + kq;
        half8 w0 = *(const half8*)(wlds + ((kc * 32 + n0) << 3));
        half8 w1 = *(const half8*)(wlds + ((kc * 32 + n1) << 3));
        acc0 = __builtin_amdgcn_mfma_f32_16x16x32_f16(aA[kt], w0, acc0, 0, 0, 0);
        acc1 = __builtin_amdgcn_mfma_f32_16x16x32_f16(aA[kt], w1, acc1, 0, 0, 0);
      }
    }

    // ---- parallel polls: wave3 = own layer step t-1, wave2 = layer below
    //      with one-step lookahead (enables next step's hoist) ----
    if (t > 0 && p == 3) {
      const int* f = cnt + l * NW;
      for (int it = 0; it < POLL_BOUND; ++it) {
        int v = ldflag_x(f + (lane & 31));
        if (__all(v >= t)) break;
        __builtin_amdgcn_s_sleep(1);
      }
    }
    if (l > 0 && p == 2) {
      const int tgt = (t + 2 < TT) ? t + 2 : TT;
      const int* f = cnt + (l - 1) * NW;
      for (int it = 0; it < POLL_BOUND; ++it) {
        int v = ldflag_x(f + (lane & 31));
        if (__all(v >= tgt)) break;
        __builtin_amdgcn_s_sleep(1);
      }
    }
    __syncthreads();   // barrier A

    // ---- t==0 input half (fwd>=2 just confirmed, covers >=1) ----
    if (l > 0 && t == 0) {
      const _Float16* ain = hin;   // t = 0
      half8 aA[8];
#pragma unroll
      for (int kt = 0; kt < 8; ++kt) {
        int kc = kt * 4 + kq;
        aA[kt] = *(const half8*)(ain + ((size_t)(kc * 64 + arow) << 3));
      }
#pragma unroll
      for (int kt = 0; kt < 8; ++kt) {
        int kc = kt * 4 + kq;
        half8 w0 = *(const half8*)(wlds + ((kc * 32 + n0) << 3));
        half8 w1 = *(const half8*)(wlds + ((kc * 32 + n1) << 3));
        acc0 = __builtin_amdgcn_mfma_f32_16x16x32_f16(aA[kt], w0, acc0, 0, 0, 0);
        acc1 = __builtin_amdgcn_mfma_f32_16x16x32_f16(aA[kt], w1, acc1, 0, 0, 0);
      }
    }

    // ---- recurrent half: load h(t-1) (L2-warm after R14's self-warm) ----
    if (t > 0) {
      const _Float16* ain = hrec + (size_t)(t - 1) * TSTRIDE;
      half8 aB[8];
#pragma unroll
      for (int kt = 0; kt < 8; ++kt) {
        int kc = kt * 4 + kq;
        aB[kt] = *(const half8*)(ain + ((size_t)(kc * 64 + arow) << 3));
      }
#pragma unroll
      for (int kt = 0; kt < 8; ++kt) {
        int kc = kt * 4 + kq;
        half8 w0 = *(const half8*)(wlds + (((32 + kc) * 32 + n0) << 3));
        half8 w1 = *(const half8*)(wlds + (((32 + kc) * 32 + n1) << 3));
        acc0 = __builtin_amdgcn_mfma_f32_16x16x32_f16(aB[kt], w0, acc0, 0, 0, 0);
        acc1 = __builtin_amdgcn_mfma_f32_16x16x32_f16(aB[kt], w1, acc1, 0, 0, 0);
      }
    }

    // ---- (J2) packed gate exchange: lanes c<->c+8 swap the two C-rows the
    //      partner needs. After this BOTH halves hold complete i/f/g/o. ----
    const float sa0 = lowh ? acc0[2] : acc0[0];
    const float sa1 = lowh ? acc0[3] : acc0[1];
    const float sb0 = lowh ? acc1[2] : acc1[0];
    const float sb1 = lowh ? acc1[3] : acc1[1];
    const float ra0 = __shfl_xor(sa0, 8);
    const float ra1 = __shfl_xor(sa1, 8);
    const float rb0 = __shfl_xor(sb0, 8);
    const float rb1 = __shfl_xor(sb1, 8);

    // ---- cell on ALL lanes: 2 cells/lane (rows rowb+roff, rowb+roff+1) ----
#pragma unroll
    for (int rr = 0; rr < 2; ++rr) {
      const int r = roff + rr;
      const float own0 = acc0[r], own1 = acc1[r];
      const float oth0 = rr ? ra1 : ra0;
      const float oth1 = rr ? rb1 : rb0;
      float gi = (lowh ? own0 : oth0) + bi;
      float gf = (lowh ? oth0 : own0) + bf;
      float gg = (lowh ? own1 : oth1) + bg;
      float go = (lowh ? oth1 : own1) + bo;
      if (l == 0) {
        const int xv = x[(rowb + r) * TT + t];
        const float* tb = tlds + xv * NR;
        gi += tb[cu]; gf += tb[8 + cu]; gg += tb[16 + cu]; go += tb[24 + cu];
      }
      const float iv = sigm(gi), fv = sigm(gf), gv = tanh_f(gg), ov = sigm(go);
      cst[rr] = fv * cst[rr] + iv * gv;
      const float hv = ov * tanh_f(cst[rr]);
      hl[(rowb + r) * 8 + cu] = (_Float16)hv;
    }
    __syncthreads();   // barrier C: hl complete

    // ---- publish: wave0 stores the 1KB slice, acks its own stores, then
    //      releases -- at raised priority (T5). Then L2 SELF-WARM: cached
    //      global_load_lds of the just-released slice into a never-read LDS
    //      sink pre-fills the XCD-shared L2 for next step's 32 consumers.
    //      Waves 1-3 run ahead to next hoist. ----
    if (tid < 64) {
      __builtin_amdgcn_s_setprio(1);
      _Float16* dst = hrec + (size_t)t * TSTRIDE + ((size_t)(w * 64 + tid) << 3);
      half8 hv = *(const half8*)(hl + tid * 8);
      gstore8_x(dst, hv);
      wait_vm0();      // wave0's h stores are at the coherence point
      if (tid == 0)
        stdword_x(cnt + l * NW + w, t + 1);   // release
      __builtin_amdgcn_s_setprio(0);
      // self-warm (post-release: data final; first read of these addresses)
      __builtin_amdgcn_global_load_lds((const u32*)dst, (u32*)warmsc, 16, 0, 0);
    }
    // next iteration's barrier A closes the step
  }
}

// ---------------------------------------------------------------------------
// Final projection via MFMA: out[b][t][v] = h7[b][t][:] . fc_w[v][:] + fc_b[v]
// h7 is stored in the exact A-fragment layout [kc][b][8]. N = 23 padded to 32
// (2 tiles). Split-precision weights: w = w_hi + w_lo * 2^-11, both fp16
// (w_lo pre-scaled by 2^11 to stay in normal range); two accumulator sets
// keep the quantization error ~2^-22 relative -- no threshold risk.
__global__ __launch_bounds__(256) void fc_kernel(
    const _Float16* __restrict__ hseq7,  // [T][32][64][8] fp16
    const float* __restrict__ fcw,       // [23][256]
    const float* __restrict__ fcb,       // [23]
    float* __restrict__ out)             // [64][512][23]
{
  const int t = blockIdx.x;
  const int tid = threadIdx.x;
  const int lane = tid & 63;
  const int p = tid >> 6;

  __shared__ __align__(16) _Float16 whi[32 * 32 * 8];  // [kc][n][8] 16KB
  __shared__ __align__(16) _Float16 wlo[32 * 32 * 8];  // residual * 2^11
  __shared__ float bbuf[32];

  for (int idx = tid; idx < 32 * 32; idx += 256) {
    int kc = idx >> 5, n = idx & 31;
    _Float16* dh = whi + (size_t)idx * 8;
    _Float16* dl = wlo + (size_t)idx * 8;
    if (n < 23) {
      const float* src = fcw + n * 256 + kc * 8;
      for (int j = 0; j < 8; ++j) {
        float v = src[j];
        _Float16 hi = (_Float16)v;
        dh[j] = hi;
        dl[j] = (_Float16)((v - (float)hi) * 2048.0f);
      }
    } else {
      for (int j = 0; j < 8; ++j) { dh[j] = (_Float16)0.f; dl[j] = (_Float16)0.f; }
    }
  }
  if (tid < 32) bbuf[tid] = (tid < 23) ? fcb[tid] : 0.f;
  __syncthreads();

  const int arow = p * 16 + (lane & 15);
  const int kq   = lane >> 4;
  const int n0   = lane & 15;
  const int n1   = 16 + n0;

  const _Float16* src = hseq7 + (size_t)t * TSTRIDE;
  floatx4 a0h = {0.f,0.f,0.f,0.f}, a1h = {0.f,0.f,0.f,0.f};
  floatx4 a0l = {0.f,0.f,0.f,0.f}, a1l = {0.f,0.f,0.f,0.f};
#pragma unroll
  for (int kt = 0; kt < 8; ++kt) {
    int kc = kt * 4 + kq;
    half8 a  = *(const half8*)(src + ((size_t)(kc * 64 + arow) << 3));
    half8 h0 = *(const half8*)(whi + ((kc * 32 + n0) << 3));
    half8 h1 = *(const half8*)(whi + ((kc * 32 + n1) << 3));
    half8 l0 = *(const half8*)(wlo + ((kc * 32 + n0) << 3));
    half8 l1 = *(const half8*)(wlo + ((kc * 32 + n1) << 3));
    a0h = __builtin_amdgcn_mfma_f32_16x16x32_f16(a, h0, a0h, 0, 0, 0);
    a1h = __builtin_amdgcn_mfma_f32_16x16x32_f16(a, h1, a1h, 0, 0, 0);
    a0l = __builtin_amdgcn_mfma_f32_16x16x32_f16(a, l0, a0l, 0, 0, 0);
    a1l = __builtin_amdgcn_mfma_f32_16x16x32_f16(a, l1, a1l, 0, 0, 0);
  }

  // C layout: col = lane&15 (vocab), row = kq*4 + r (+p*16) (batch)
  const float rs = 1.0f / 2048.0f;
#pragma unroll
  for (int r = 0; r < 4; ++r) {
    int b = p * 16 + kq * 4 + r;
    out[((size_t)b * TT + t) * 23 + n0] = a0h[r] + a0l[r] * rs + bbuf[n0];
    if (n1 < 23)
      out[((size_t)b * TT + t) * 23 + n1] = a1h[r] + a1l[r] * rs + bbuf[n1];
  }
}

// ---------------------------------------------------------------------------
extern "C" void kernel_launch(void* const* d_in, const int* in_sizes, int n_in,
                              void* d_out, int out_size, void* d_ws, size_t ws_size,
                              hipStream_t stream) {
  const int*   x        = (const int*)d_in[0];
  const float* emb      = (const float*)d_in[1];
  const float* Wih0     = (const float*)d_in[2];
  const float* Wih_rest = (const float*)d_in[3];
  const float* Whh      = (const float*)d_in[4];
  const float* bihp     = (const float*)d_in[5];
  const float* bhhp     = (const float*)d_in[6];
  const float* fcw      = (const float*)d_in[7];
  const float* fcb      = (const float*)d_in[8];
  float* out = (float*)d_out;

  char* ws = (char*)d_ws;
  // ws layout (proven): cnt @0 (1KB used) | table @16384 | hseq @131072 (128MB)
  int*      cnt   = (int*)ws;
  float*    table = (float*)(ws + 16384);              // 23*1024*4 = 94208 B
  _Float16* hseq  = (_Float16*)(ws + 131072);          // 8 * 16 MB

  hipMemsetAsync(ws, 0, 16384, stream);  // counters
  build_xg0<<<(23 * G4 + 255) / 256, 256, 0, stream>>>(emb, Wih0, table);
  lstm_pipeline<<<NL * NW, 256, 0, stream>>>(x, Wih_rest, Whh, bihp, bhhp, table, hseq, cnt);
  fc_kernel<<<TT, 256, 0, stream>>>(hseq + (size_t)7 * LSTRIDE, fcw, fcb, out);
}